// Round 19
// baseline (146.577 us; speedup 1.0000x reference)
//
#include <hip/hip_runtime.h>
#include <math.h>

// Problem constants
#define N_ROWS   16384            // 32*512
#define DIM      64
#define K_CODES  8192
#define SPLITS   8
#define KC       (K_CODES / SPLITS)   // 1024 codes per split
#define CH       64                   // codes per LDS chunk (two 32-code MFMA tiles)
#define NCH      (KC / CH)            // 16 chunks
#define CSTRIDE  200                  // ushorts per code row in cs (400 B; 192 data + 8 pad)
#define RPB      256                  // rows per block (64 per wave: two 32-row sets)
#define RBLK     (N_ROWS / RPB)       // 64 row-blocks

// Output layout (flat float32): loss | quantized | perplexity | encodings
#define OFF_LOSS 0
#define OFF_Q    1
#define OFF_P    1048577
#define OFF_E    1048578
#define ZBASE    1048576              // 16B-aligned base for bulk zero-fill (f4 units below)
// zero-fill region split (in float4 units, relative to ZBASE)  [R16's proven split]:
//   argmin   [0, 29360128)          : zeroed in kernel 2, ones in kernel 3
//   prologue [29360128, 31457280)   : zeroed in kernel 1, ones in kernel 3
//   finalize [31457280, 33554432)   : zeroed in kernel 3, ones in kernel 4 (rows>=15359)
#define ZF4_ARG_PER_BLOCK 57344       // 29360128 / 512 blocks = 224/thread = 14/chunk
#define ZF4_PRO_BASE 29360128u
#define ZF4_FIN_BASE 31457280u
#define ZF4_FIN_PER_BLOCK 4096        // 2097152 / 512 finalize blocks
#define ROW_LATE 15359                // rows >= this get their 1.0 from scalars kernel

// Workspace layout (bytes); total ~3.47 MB
#define WS_CS    0                              // 8192*200*2 = 3276800
#define WS_E2H   3276800                        // 8192 f32 = 32768
#define WS_KEY   (3276800 + 32768)              // 16384 u64 = 131072
#define WS_HIST  (3276800 + 32768 + 131072)     // 8192 int = 32768
#define WS_LOSS  (3276800 + 32768 + 131072 + 32768)

using bf16x8 = __attribute__((ext_vector_type(8))) short;
using f32x16 = __attribute__((ext_vector_type(16))) float;
typedef float vfloat4 __attribute__((ext_vector_type(4)));

static __device__ __forceinline__ unsigned short f2bf(float f) {
  unsigned int u = __float_as_uint(f);
  u = u + 0x7FFFu + ((u >> 16) & 1u);   // round-to-nearest-even
  return (unsigned short)(u >> 16);
}
static __device__ __forceinline__ float bf2f(unsigned short h) {
  return __uint_as_float(((unsigned int)h) << 16);
}

// ---------------- fused prologue: csplit + e2h + inits + 32MB zero share ----------------
__global__ __launch_bounds__(256) void vq_prologue_kernel(
    const float* __restrict__ cb, unsigned short* __restrict__ cs,
    float* __restrict__ e2h, unsigned long long* __restrict__ rowkey,
    int* __restrict__ hist, float* __restrict__ lossSum,
    float* __restrict__ outp) {
  const int gid = blockIdx.x * 256 + threadIdx.x;   // 65536 total

  // --- csplit: 8 threads per code, 8 d-elements each ---
  {
    const int code = gid >> 3;
    const int dq = (gid & 7) << 3;
    const float* s = cb + (size_t)code * 64 + dq;
    const float4 a = *(const float4*)s;
    const float4 b = *(const float4*)(s + 4);
    const float v[8] = {a.x, a.y, a.z, a.w, b.x, b.y, b.z, b.w};
    union { unsigned short u[8]; uint4 q; } h1, h2, h3;
#pragma unroll
    for (int j = 0; j < 8; ++j) {
      const float f = v[j];
      const unsigned short b1 = f2bf(f);  const float r  = f - bf2f(b1);
      const unsigned short b2 = f2bf(r);  const float r2 = r - bf2f(b2);
      const unsigned short b3 = f2bf(r2);
      h1.u[j] = b1; h2.u[j] = b2; h3.u[j] = b3;
    }
    unsigned short* base = cs + (size_t)code * CSTRIDE;
    *(uint4*)(base + 0 * 64 + dq) = h1.q;   // byte = code*400 + s*128 + dq*2 -> 16B aligned
    *(uint4*)(base + 1 * 64 + dq) = h2.q;
    *(uint4*)(base + 2 * 64 + dq) = h3.q;
  }

  // --- e2h = -0.5*||e||^2 (exact fp32) ---
  if (gid < K_CODES) {
    const float4* e = reinterpret_cast<const float4*>(cb + ((size_t)gid << 6));
    float s0 = 0.f, s1 = 0.f, s2 = 0.f, s3 = 0.f;
#pragma unroll
    for (int i = 0; i < DIM / 4; ++i) {
      float4 v = e[i];
      s0 = fmaf(v.x, v.x, s0);
      s1 = fmaf(v.y, v.y, s1);
      s2 = fmaf(v.z, v.z, s2);
      s3 = fmaf(v.w, v.w, s3);
    }
    e2h[gid] = -0.5f * ((s0 + s1) + (s2 + s3));
  }

  // --- inits (ws not re-poisoned between replays -> must re-init every call) ---
  if (gid < N_ROWS) rowkey[gid] = ~0ULL;
  if (gid < K_CODES) hist[gid] = 0;
  if (gid == 0) {
    lossSum[0] = 0.0f;
    outp[135266304] = 0.0f;   // two tail floats beyond the float4 bulk zero region
    outp[135266305] = 0.0f;
  }

  // --- 32 MB encodings zero share (keeps write pipe busy during prologue) ---
  {
    vfloat4* zp = (vfloat4*)(outp + ZBASE) + ZF4_PRO_BASE + gid;
    const vfloat4 zz = (vfloat4)(0.0f);
#pragma unroll
    for (int j = 0; j < 32; ++j)
      __builtin_nontemporal_store(zz, zp + (size_t)j * 65536);
  }
}

// ---------------- MFMA argmin: 2 row-sets/wave, shared staging, raw barriers -------------
// (exact R10/R16 form -- best measured; 448MB fused fill = at the free-overlap margin)
// acc' = dot(x,e) - ||e||^2/2 ; argmin dist == argmax acc'.
__global__ __launch_bounds__(256, 2) void vq_argmin_kernel(
    const float* __restrict__ x, const unsigned short* __restrict__ cs,
    const float* __restrict__ e2h, unsigned long long* __restrict__ rowkey,
    float* __restrict__ outp) {
  const int tid  = threadIdx.x;
  const int lane = tid & 63, wave = tid >> 6;
  const int g    = lane >> 5, c32 = lane & 31;
  const int sp   = blockIdx.y;
  const int k0   = sp * KC;
  const int myrow0 = blockIdx.x * RPB + wave * 32 + c32;   // row-set A
  const int myrow1 = myrow0 + 128;                          // row-set B

  __shared__ __align__(16) unsigned short Alds[CH * CSTRIDE];   // 25600 B
  __shared__ float e2l[KC];                                     // 4096 B

  // stage this split's -e2/2 (ds_writes covered by chunk-0's lgkmcnt(0)+barrier)
#pragma unroll
  for (int i = 0; i < KC / 256; ++i) e2l[i * 256 + tid] = e2h[k0 + i * 256 + tid];

  // B-side (x) fragments for both row-sets: 2 x 3 bf16-splits x 4 k-steps (96 VGPRs).
  // lane -> (col = c32 = x-row, k-chunk = g*8 within each 16-k step).
  bf16x8 xfA[3][4], xfB[3][4];
#pragma unroll
  for (int rs = 0; rs < 2; ++rs) {
    const float* xp = x + ((size_t)(rs ? myrow1 : myrow0) << 6);
#pragma unroll
    for (int t = 0; t < 4; ++t) {
      const float* p = xp + t * 16 + g * 8;
      const float4 a = *(const float4*)p;
      const float4 b = *(const float4*)(p + 4);
      const float v[8] = {a.x, a.y, a.z, a.w, b.x, b.y, b.z, b.w};
      union { unsigned short u[8]; bf16x8 f; } u1, u2, u3;
#pragma unroll
      for (int j = 0; j < 8; ++j) {
        const float f = v[j];
        const unsigned short b1 = f2bf(f);  const float r  = f - bf2f(b1);
        const unsigned short b2 = f2bf(r);  const float r2 = r - bf2f(b2);
        const unsigned short b3 = f2bf(r2);
        u1.u[j] = b1; u2.u[j] = b2; u3.u[j] = b3;
      }
      if (rs == 0) { xfA[0][t] = u1.f; xfA[1][t] = u2.f; xfA[2][t] = u3.f; }
      else         { xfB[0][t] = u1.f; xfB[1][t] = u2.f; xfB[2][t] = u3.f; }
    }
  }

  // fused encodings zero-fill (nontemporal; 224 float4/thread, 14 per chunk)
  const int blin = sp * gridDim.x + blockIdx.x;   // 0..511
  vfloat4* zdst = (vfloat4*)(outp + ZBASE) + (size_t)blin * ZF4_ARG_PER_BLOCK + tid;
  const vfloat4 zz = (vfloat4)(0.0f);

  float bestA = -3.4e38f, bestB = -3.4e38f;   // argmax of acc'
  int   biA = 0, biB = 0;

  for (int ch = 0; ch < NCH; ++ch) {
    const int cl = ch * CH;
    // ---- 1) stage loads to regs (25600 B = 1600 x 16B; 6 full rounds + 64-thread tail)
    const uint4* src = (const uint4*)(cs + (size_t)(k0 + cl) * CSTRIDE);
    uint4 st[6], stT;
#pragma unroll
    for (int j = 0; j < 6; ++j) st[j] = src[j * 256 + tid];
    if (tid < 64) stT = src[1536 + tid];
    // ---- 2) NT stores AFTER loads: counted vmcnt for the ds_writes leaves them in flight
#pragma unroll
    for (int u = 0; u < 14; ++u)
      __builtin_nontemporal_store(zz, zdst + (size_t)(ch * 14 + u) * 256);
    // ---- 3) LDS writes
    {
      uint4* dst = (uint4*)Alds;
#pragma unroll
      for (int j = 0; j < 6; ++j) dst[j * 256 + tid] = st[j];
      if (tid < 64) dst[1536 + tid] = stT;
    }
    // ---- 4) cross-wave visibility: lgkmcnt only (NOT vmcnt -> stores keep flowing)
    __builtin_amdgcn_sched_barrier(0);
    asm volatile("s_waitcnt lgkmcnt(0)" ::: "memory");
    __builtin_amdgcn_s_barrier();
    __builtin_amdgcn_sched_barrier(0);

    // ---- 5) compute two 32-code tiles; A-frags + e2 read ONCE, used for both row-sets
#pragma unroll
    for (int kt = 0; kt < 2; ++kt) {
      const int clk = cl + kt * 32;
      // e2 init values: C row(code) = (reg&3) + 8*(reg>>2) + 4*g  (reg = 4q+r)
      f32x16 accA, accB;
#pragma unroll
      for (int q = 0; q < 4; ++q) {
        const float4 e4 = *(const float4*)(e2l + clk + q * 8 + g * 4);
        accA[4 * q + 0] = e4.x; accA[4 * q + 1] = e4.y;
        accA[4 * q + 2] = e4.z; accA[4 * q + 3] = e4.w;
        accB[4 * q + 0] = e4.x; accB[4 * q + 1] = e4.y;
        accB[4 * q + 2] = e4.z; accB[4 * q + 3] = e4.w;
      }
      // A-side (codes) fragments: row = c32, k-chunk = g*8 (same lane->k map as B-side,
      // so any k-permutation error cancels in A.B)
      const unsigned short* ab = Alds + (size_t)(kt * 32 + c32) * CSTRIDE + g * 8;
      bf16x8 af0[4], af1[4], af2[4];
#pragma unroll
      for (int t = 0; t < 4; ++t) {
        af0[t] = *(const bf16x8*)(ab + 0 * 64 + t * 16);
        af1[t] = *(const bf16x8*)(ab + 1 * 64 + t * 16);
        af2[t] = *(const bf16x8*)(ab + 2 * 64 + t * 16);
      }
      // 6 split-products x 4 k-steps x 2 row-sets = 48 MFMA; two independent acc chains
#pragma unroll
      for (int t = 0; t < 4; ++t) {
        accA = __builtin_amdgcn_mfma_f32_32x32x16_bf16(af0[t], xfA[0][t], accA, 0, 0, 0);
        accB = __builtin_amdgcn_mfma_f32_32x32x16_bf16(af0[t], xfB[0][t], accB, 0, 0, 0);
        accA = __builtin_amdgcn_mfma_f32_32x32x16_bf16(af1[t], xfA[0][t], accA, 0, 0, 0);
        accB = __builtin_amdgcn_mfma_f32_32x32x16_bf16(af1[t], xfB[0][t], accB, 0, 0, 0);
        accA = __builtin_amdgcn_mfma_f32_32x32x16_bf16(af0[t], xfA[1][t], accA, 0, 0, 0);
        accB = __builtin_amdgcn_mfma_f32_32x32x16_bf16(af0[t], xfB[1][t], accB, 0, 0, 0);
        accA = __builtin_amdgcn_mfma_f32_32x32x16_bf16(af1[t], xfA[1][t], accA, 0, 0, 0);
        accB = __builtin_amdgcn_mfma_f32_32x32x16_bf16(af1[t], xfB[1][t], accB, 0, 0, 0);
        accA = __builtin_amdgcn_mfma_f32_32x32x16_bf16(af2[t], xfA[0][t], accA, 0, 0, 0);
        accB = __builtin_amdgcn_mfma_f32_32x32x16_bf16(af2[t], xfB[0][t], accB, 0, 0, 0);
        accA = __builtin_amdgcn_mfma_f32_32x32x16_bf16(af0[t], xfA[2][t], accA, 0, 0, 0);
        accB = __builtin_amdgcn_mfma_f32_32x32x16_bf16(af0[t], xfB[2][t], accB, 0, 0, 0);
      }
      // epilogue: running argmax; codes ascending within lane (first-max == first-min dist)
      const int cg = k0 + clk + 4 * g;
#pragma unroll
      for (int q = 0; q < 4; ++q) {
#pragma unroll
        for (int r = 0; r < 4; ++r) {
          const int code = cg + 8 * q + r;
          const float vA = accA[4 * q + r];
          const bool cA = vA > bestA;
          bestA = cA ? vA : bestA;
          biA   = cA ? code : biA;
          const float vB = accB[4 * q + r];
          const bool cB = vB > bestB;
          bestB = cB ? vB : bestB;
          biB   = cB ? code : biB;
        }
      }
    }
    // ---- 6) end-of-compute barrier (raw: no vmcnt drain) before next overwrite ----
    __builtin_amdgcn_sched_barrier(0);
    __builtin_amdgcn_s_barrier();
    __builtin_amdgcn_sched_barrier(0);
  }

  // combine the two half-code-sets (lanes l and l^32 share x-row = lane&31)
  {
    const float ob = __shfl_xor(bestA, 32, 64);
    const int   oi = __shfl_xor(biA,   32, 64);
    if (ob > bestA || (ob == bestA && oi < biA)) { bestA = ob; biA = oi; }
  }
  {
    const float ob = __shfl_xor(bestB, 32, 64);
    const int   oi = __shfl_xor(biB,   32, 64);
    if (ob > bestB || (ob == bestB && oi < biB)) { bestB = ob; biB = oi; }
  }
  if (lane < 32) {
    // bijective monotone float->uint transform: unsigned order == float order
    const float distA = -2.0f * bestA;   // can be negative
    unsigned int dA = __float_as_uint(distA);
    dA ^= (unsigned int)((int)dA >> 31) | 0x80000000u;
    atomicMin(rowkey + myrow0,
              ((unsigned long long)dA << 32) | (unsigned int)biA);
    const float distB = -2.0f * bestB;
    unsigned int dB = __float_as_uint(distB);
    dB ^= (unsigned int)((int)dB >> 31) | 0x80000000u;
    atomicMin(rowkey + myrow1,
              ((unsigned long long)dB << 32) | (unsigned int)biB);
  }
}

// ---------------- finalize (WIDE): 512 blocks, 8 thr/row + 32MB zero share --------------
// 8x the parallelism of the 64-block version; fill issued first, drains under gather.
// One-hots for rows >= ROW_LATE (may land in THIS kernel's zero region) come from the
// scalars kernel afterwards -> no intra-kernel race.
__global__ __launch_bounds__(256) void vq_finalize_rows_kernel(
    const float* __restrict__ x, const float* __restrict__ cb,
    const unsigned long long* __restrict__ rowkey,
    int* __restrict__ hist, float* __restrict__ lossSum,
    float* __restrict__ outp) {
  const int tid = threadIdx.x;

  // 32 MB zero share (NT)
  {
    vfloat4* zp = (vfloat4*)(outp + ZBASE) + ZF4_FIN_BASE
                + (size_t)blockIdx.x * ZF4_FIN_PER_BLOCK + tid;
    const vfloat4 zz = (vfloat4)(0.0f);
#pragma unroll
    for (int j = 0; j < 16; ++j)
      __builtin_nontemporal_store(zz, zp + (size_t)j * 256);
  }

  const int row = blockIdx.x * 32 + (tid >> 3);   // 32 rows/block
  const int sub = tid & 7;                        // 8 threads/row, 8 floats each
  const int bi = (int)(rowkey[row] & 0xFFFFFFFFull);

  if (sub == 0) {
    atomicAdd(hist + bi, 1);
    if (row < ROW_LATE)
      outp[(size_t)OFF_E + (size_t)row * K_CODES + bi] = 1.0f;
  }

  const float4* ecb = (const float4*)(cb + ((size_t)bi << 6) + sub * 8);
  const float4* xv  = (const float4*)(x + ((size_t)row << 6) + sub * 8);
  const float4 e0 = ecb[0], e1 = ecb[1];
  const float4 x0 = xv[0],  x1 = xv[1];
  float* q = outp + OFF_Q + (size_t)row * DIM + sub * 8;  // 4B-aligned -> scalar stores
  q[0] = e0.x; q[1] = e0.y; q[2] = e0.z; q[3] = e0.w;
  q[4] = e1.x; q[5] = e1.y; q[6] = e1.z; q[7] = e1.w;
  float ls = 0.f;
  {
    const float d0 = e0.x - x0.x, d1 = e0.y - x0.y;
    const float d2 = e0.z - x0.z, d3 = e0.w - x0.w;
    const float d4 = e1.x - x1.x, d5 = e1.y - x1.y;
    const float d6 = e1.z - x1.z, d7 = e1.w - x1.w;
    ls = fmaf(d0, d0, ls); ls = fmaf(d1, d1, ls);
    ls = fmaf(d2, d2, ls); ls = fmaf(d3, d3, ls);
    ls = fmaf(d4, d4, ls); ls = fmaf(d5, d5, ls);
    ls = fmaf(d6, d6, ls); ls = fmaf(d7, d7, ls);
  }
  // per-wave reduction, one atomic per wave
#pragma unroll
  for (int off = 32; off > 0; off >>= 1) ls += __shfl_down(ls, off, 64);
  if ((tid & 63) == 0) atomicAdd(lossSum, ls);
}

// ---------------- scalars: loss + perplexity; late one-hots parallel over 8 blocks ------
__global__ __launch_bounds__(256) void vq_scalars_kernel(
    const int* __restrict__ hist, const float* __restrict__ lossSum,
    const unsigned long long* __restrict__ rowkey,
    float* __restrict__ outp) {
  // late one-hots (rows whose encodings f4 may fall in finalize's zero region)
  {
    const int idx = blockIdx.x * 256 + threadIdx.x;   // 0..2047
    const int r = ROW_LATE + idx;
    if (r < N_ROWS) {
      const int bi = (int)(rowkey[r] & 0xFFFFFFFFull);
      outp[(size_t)OFF_E + (size_t)r * K_CODES + bi] = 1.0f;
    }
  }
  if (blockIdx.x != 0) return;

  __shared__ float red[256];
  float s = 0.f;
  for (int k = threadIdx.x; k < K_CODES; k += 256) {
    const float p = (float)hist[k] * (1.0f / (float)N_ROWS);
    s += p * logf(p + 1e-10f);
  }
  red[threadIdx.x] = s;
  __syncthreads();
  for (int off = 128; off > 0; off >>= 1) {
    if (threadIdx.x < off) red[threadIdx.x] += red[threadIdx.x + off];
    __syncthreads();
  }
  if (threadIdx.x == 0) {
    outp[OFF_P] = expf(-red[0]);
    outp[OFF_LOSS] = 0.25f * lossSum[0] * (1.0f / 1048576.0f);
  }
}

extern "C" void kernel_launch(void* const* d_in, const int* in_sizes, int n_in,
                              void* d_out, int out_size, void* d_ws, size_t ws_size,
                              hipStream_t stream) {
  const float* x  = (const float*)d_in[0];   // [16384, 64]
  const float* cb = (const float*)d_in[1];   // [8192, 64]
  float* outp = (float*)d_out;

  char* wsb = (char*)d_ws;
  unsigned short* cs          = (unsigned short*)(wsb + WS_CS);
  float* e2h                  = (float*)(wsb + WS_E2H);
  unsigned long long* rowkey  = (unsigned long long*)(wsb + WS_KEY);
  int*   hist                 = (int*)(wsb + WS_HIST);
  float* lossSum              = (float*)(wsb + WS_LOSS);

  vq_prologue_kernel<<<256, 256, 0, stream>>>(cb, cs, e2h, rowkey, hist, lossSum, outp);
  vq_argmin_kernel<<<dim3(RBLK, SPLITS), 256, 0, stream>>>(x, cs, e2h, rowkey, outp);
  vq_finalize_rows_kernel<<<N_ROWS / 32, 256, 0, stream>>>(x, cb, rowkey, hist, lossSum, outp);
  vq_scalars_kernel<<<8, 256, 0, stream>>>(hist, lossSum, rowkey, outp);
}

// Round 20
// 134.706 us; speedup vs baseline: 1.0881x; 1.0881x over previous
//
#include <hip/hip_runtime.h>
#include <math.h>

// Problem constants
#define N_ROWS   16384            // 32*512
#define DIM      64
#define K_CODES  8192
#define SPLITS   8
#define KC       (K_CODES / SPLITS)   // 1024 codes per split
#define CH       64                   // codes per LDS chunk (two 32-code MFMA tiles)
#define NCH      (KC / CH)            // 16 chunks
#define CSTRIDE  200                  // ushorts per code row in cs (400 B; 192 data + 8 pad)
#define RPB      256                  // rows per block (64 per wave: two 32-row sets)
#define RBLK     (N_ROWS / RPB)       // 64 row-blocks

// Output layout (flat float32): loss | quantized | perplexity | encodings
#define OFF_LOSS 0
#define OFF_Q    1
#define OFF_P    1048577
#define OFF_E    1048578
#define ZBASE    1048576              // 16B-aligned base for bulk zero-fill (f4 units below)
// zero-fill region split (in float4 units, relative to ZBASE):
//   argmin   [0, 29360128)          : zeroed in kernel 2, ones in kernel 3
//   prologue [29360128, 31457280)   : zeroed in kernel 1, ones in kernel 3
//   finalize [31457280, 33554432)   : zeroed in kernel 3, ones in kernel 4 (rows>=15359)
#define ZF4_ARG_PER_BLOCK 57344       // 29360128 / 1024 blocks = 112/thread = 7/chunk
#define ZF4_PRO_BASE 29360128u
#define ZF4_FIN_BASE 31457280u
#define ROW_LATE 15359                // rows >= this get their 1.0 from scalars kernel

// Workspace layout (bytes); total ~3.47 MB
#define WS_CS    0                              // 8192*200*2 = 3276800
#define WS_E2H   3276800                        // 8192 f32 = 32768
#define WS_KEY   (3276800 + 32768)              // 16384 u64 = 131072
#define WS_HIST  (3276800 + 32768 + 131072)     // 8192 int = 32768
#define WS_LOSS  (3276800 + 32768 + 131072 + 32768)

using bf16x8 = __attribute__((ext_vector_type(8))) short;
using f32x16 = __attribute__((ext_vector_type(16))) float;
typedef float vfloat4 __attribute__((ext_vector_type(4)));

static __device__ __forceinline__ unsigned short f2bf(float f) {
  unsigned int u = __float_as_uint(f);
  u = u + 0x7FFFu + ((u >> 16) & 1u);   // round-to-nearest-even
  return (unsigned short)(u >> 16);
}
static __device__ __forceinline__ float bf2f(unsigned short h) {
  return __uint_as_float(((unsigned int)h) << 16);
}

// ---------------- fused prologue: csplit + e2h + inits + 32MB zero share ----------------
__global__ __launch_bounds__(256) void vq_prologue_kernel(
    const float* __restrict__ cb, unsigned short* __restrict__ cs,
    float* __restrict__ e2h, unsigned long long* __restrict__ rowkey,
    int* __restrict__ hist, float* __restrict__ lossSum,
    float* __restrict__ outp) {
  const int gid = blockIdx.x * 256 + threadIdx.x;   // 65536 total

  // --- csplit: 8 threads per code, 8 d-elements each ---
  {
    const int code = gid >> 3;
    const int dq = (gid & 7) << 3;
    const float* s = cb + (size_t)code * 64 + dq;
    const float4 a = *(const float4*)s;
    const float4 b = *(const float4*)(s + 4);
    const float v[8] = {a.x, a.y, a.z, a.w, b.x, b.y, b.z, b.w};
    union { unsigned short u[8]; uint4 q; } h1, h2, h3;
#pragma unroll
    for (int j = 0; j < 8; ++j) {
      const float f = v[j];
      const unsigned short b1 = f2bf(f);  const float r  = f - bf2f(b1);
      const unsigned short b2 = f2bf(r);  const float r2 = r - bf2f(b2);
      const unsigned short b3 = f2bf(r2);
      h1.u[j] = b1; h2.u[j] = b2; h3.u[j] = b3;
    }
    unsigned short* base = cs + (size_t)code * CSTRIDE;
    *(uint4*)(base + 0 * 64 + dq) = h1.q;   // byte = code*400 + s*128 + dq*2 -> 16B aligned
    *(uint4*)(base + 1 * 64 + dq) = h2.q;
    *(uint4*)(base + 2 * 64 + dq) = h3.q;
  }

  // --- e2h = -0.5*||e||^2 (exact fp32) ---
  if (gid < K_CODES) {
    const float4* e = reinterpret_cast<const float4*>(cb + ((size_t)gid << 6));
    float s0 = 0.f, s1 = 0.f, s2 = 0.f, s3 = 0.f;
#pragma unroll
    for (int i = 0; i < DIM / 4; ++i) {
      float4 v = e[i];
      s0 = fmaf(v.x, v.x, s0);
      s1 = fmaf(v.y, v.y, s1);
      s2 = fmaf(v.z, v.z, s2);
      s3 = fmaf(v.w, v.w, s3);
    }
    e2h[gid] = -0.5f * ((s0 + s1) + (s2 + s3));
  }

  // --- inits (ws not re-poisoned between replays -> must re-init every call) ---
  if (gid < N_ROWS) rowkey[gid] = ~0ULL;
  if (gid < K_CODES) hist[gid] = 0;
  if (gid == 0) {
    lossSum[0] = 0.0f;
    outp[135266304] = 0.0f;   // two tail floats beyond the float4 bulk zero region
    outp[135266305] = 0.0f;
  }

  // --- 32 MB encodings zero share (keeps write pipe busy during prologue) ---
  {
    vfloat4* zp = (vfloat4*)(outp + ZBASE) + ZF4_PRO_BASE + gid;
    const vfloat4 zz = (vfloat4)(0.0f);
#pragma unroll
    for (int j = 0; j < 32; ++j)
      __builtin_nontemporal_store(zz, zp + (size_t)j * 65536);
  }
}

// ---------------- MFMA argmin: 2 row-sets/wave, shared staging, raw barriers -------------
// (exact R10 form -- best measured: 135.2 us total)
// Block: 256 thr = 4 waves; each wave owns 64 x-rows as TWO 32-row sets sharing one
// A-fragment read (codes from LDS) and one e2 read -> LDS bytes per MFMA halve,
// stores per chunk double (14/thread) -> store pipe stays fed.
// Raw s_barrier + lgkmcnt(0) (not __syncthreads) avoids draining the NT store queue.
// acc' = dot(x,e) - ||e||^2/2 ; argmin dist == argmax acc'.
__global__ __launch_bounds__(256, 2) void vq_argmin_kernel(
    const float* __restrict__ x, const unsigned short* __restrict__ cs,
    const float* __restrict__ e2h, unsigned long long* __restrict__ rowkey,
    float* __restrict__ outp) {
  const int tid  = threadIdx.x;
  const int lane = tid & 63, wave = tid >> 6;
  const int g    = lane >> 5, c32 = lane & 31;
  const int sp   = blockIdx.y;
  const int k0   = sp * KC;
  const int myrow0 = blockIdx.x * RPB + wave * 32 + c32;   // row-set A
  const int myrow1 = myrow0 + 128;                          // row-set B

  __shared__ __align__(16) unsigned short Alds[CH * CSTRIDE];   // 25600 B
  __shared__ float e2l[KC];                                     // 4096 B

  // stage this split's -e2/2 (ds_writes covered by chunk-0's lgkmcnt(0)+barrier)
#pragma unroll
  for (int i = 0; i < KC / 256; ++i) e2l[i * 256 + tid] = e2h[k0 + i * 256 + tid];

  // B-side (x) fragments for both row-sets: 2 x 3 bf16-splits x 4 k-steps (96 VGPRs).
  // lane -> (col = c32 = x-row, k-chunk = g*8 within each 16-k step).
  bf16x8 xfA[3][4], xfB[3][4];
#pragma unroll
  for (int rs = 0; rs < 2; ++rs) {
    const float* xp = x + ((size_t)(rs ? myrow1 : myrow0) << 6);
#pragma unroll
    for (int t = 0; t < 4; ++t) {
      const float* p = xp + t * 16 + g * 8;
      const float4 a = *(const float4*)p;
      const float4 b = *(const float4*)(p + 4);
      const float v[8] = {a.x, a.y, a.z, a.w, b.x, b.y, b.z, b.w};
      union { unsigned short u[8]; bf16x8 f; } u1, u2, u3;
#pragma unroll
      for (int j = 0; j < 8; ++j) {
        const float f = v[j];
        const unsigned short b1 = f2bf(f);  const float r  = f - bf2f(b1);
        const unsigned short b2 = f2bf(r);  const float r2 = r - bf2f(b2);
        const unsigned short b3 = f2bf(r2);
        u1.u[j] = b1; u2.u[j] = b2; u3.u[j] = b3;
      }
      if (rs == 0) { xfA[0][t] = u1.f; xfA[1][t] = u2.f; xfA[2][t] = u3.f; }
      else         { xfB[0][t] = u1.f; xfB[1][t] = u2.f; xfB[2][t] = u3.f; }
    }
  }

  // fused encodings zero-fill (nontemporal; 224 float4/thread, 14 per chunk)
  const int blin = sp * gridDim.x + blockIdx.x;   // 0..511
  vfloat4* zdst = (vfloat4*)(outp + ZBASE) + (size_t)blin * ZF4_ARG_PER_BLOCK + tid;
  const vfloat4 zz = (vfloat4)(0.0f);

  float bestA = -3.4e38f, bestB = -3.4e38f;   // argmax of acc'
  int   biA = 0, biB = 0;

  for (int ch = 0; ch < NCH; ++ch) {
    const int cl = ch * CH;
    // ---- 1) stage loads to regs (25600 B = 1600 x 16B; 6 full rounds + 64-thread tail)
    const uint4* src = (const uint4*)(cs + (size_t)(k0 + cl) * CSTRIDE);
    uint4 st[6], stT;
#pragma unroll
    for (int j = 0; j < 6; ++j) st[j] = src[j * 256 + tid];
    if (tid < 64) stT = src[1536 + tid];
    // ---- 2) NT stores AFTER loads: counted vmcnt for the ds_writes leaves them in flight
#pragma unroll
    for (int u = 0; u < 14; ++u)
      __builtin_nontemporal_store(zz, zdst + (size_t)(ch * 14 + u) * 256);
    // ---- 3) LDS writes
    {
      uint4* dst = (uint4*)Alds;
#pragma unroll
      for (int j = 0; j < 6; ++j) dst[j * 256 + tid] = st[j];
      if (tid < 64) dst[1536 + tid] = stT;
    }
    // ---- 4) cross-wave visibility: lgkmcnt only (NOT vmcnt -> stores keep flowing)
    __builtin_amdgcn_sched_barrier(0);
    asm volatile("s_waitcnt lgkmcnt(0)" ::: "memory");
    __builtin_amdgcn_s_barrier();
    __builtin_amdgcn_sched_barrier(0);

    // ---- 5) compute two 32-code tiles; A-frags + e2 read ONCE, used for both row-sets
#pragma unroll
    for (int kt = 0; kt < 2; ++kt) {
      const int clk = cl + kt * 32;
      // e2 init values: C row(code) = (reg&3) + 8*(reg>>2) + 4*g  (reg = 4q+r)
      f32x16 accA, accB;
#pragma unroll
      for (int q = 0; q < 4; ++q) {
        const float4 e4 = *(const float4*)(e2l + clk + q * 8 + g * 4);
        accA[4 * q + 0] = e4.x; accA[4 * q + 1] = e4.y;
        accA[4 * q + 2] = e4.z; accA[4 * q + 3] = e4.w;
        accB[4 * q + 0] = e4.x; accB[4 * q + 1] = e4.y;
        accB[4 * q + 2] = e4.z; accB[4 * q + 3] = e4.w;
      }
      // A-side (codes) fragments: row = c32, k-chunk = g*8 (same lane->k map as B-side,
      // so any k-permutation error cancels in A.B)
      const unsigned short* ab = Alds + (size_t)(kt * 32 + c32) * CSTRIDE + g * 8;
      bf16x8 af0[4], af1[4], af2[4];
#pragma unroll
      for (int t = 0; t < 4; ++t) {
        af0[t] = *(const bf16x8*)(ab + 0 * 64 + t * 16);
        af1[t] = *(const bf16x8*)(ab + 1 * 64 + t * 16);
        af2[t] = *(const bf16x8*)(ab + 2 * 64 + t * 16);
      }
      // 6 split-products x 4 k-steps x 2 row-sets = 48 MFMA; two independent acc chains
#pragma unroll
      for (int t = 0; t < 4; ++t) {
        accA = __builtin_amdgcn_mfma_f32_32x32x16_bf16(af0[t], xfA[0][t], accA, 0, 0, 0);
        accB = __builtin_amdgcn_mfma_f32_32x32x16_bf16(af0[t], xfB[0][t], accB, 0, 0, 0);
        accA = __builtin_amdgcn_mfma_f32_32x32x16_bf16(af1[t], xfA[0][t], accA, 0, 0, 0);
        accB = __builtin_amdgcn_mfma_f32_32x32x16_bf16(af1[t], xfB[0][t], accB, 0, 0, 0);
        accA = __builtin_amdgcn_mfma_f32_32x32x16_bf16(af0[t], xfA[1][t], accA, 0, 0, 0);
        accB = __builtin_amdgcn_mfma_f32_32x32x16_bf16(af0[t], xfB[1][t], accB, 0, 0, 0);
        accA = __builtin_amdgcn_mfma_f32_32x32x16_bf16(af1[t], xfA[1][t], accA, 0, 0, 0);
        accB = __builtin_amdgcn_mfma_f32_32x32x16_bf16(af1[t], xfB[1][t], accB, 0, 0, 0);
        accA = __builtin_amdgcn_mfma_f32_32x32x16_bf16(af2[t], xfA[0][t], accA, 0, 0, 0);
        accB = __builtin_amdgcn_mfma_f32_32x32x16_bf16(af2[t], xfB[0][t], accB, 0, 0, 0);
        accA = __builtin_amdgcn_mfma_f32_32x32x16_bf16(af0[t], xfA[2][t], accA, 0, 0, 0);
        accB = __builtin_amdgcn_mfma_f32_32x32x16_bf16(af0[t], xfB[2][t], accB, 0, 0, 0);
      }
      // epilogue: running argmax; codes ascending within lane (first-max == first-min dist)
      const int cg = k0 + clk + 4 * g;
#pragma unroll
      for (int q = 0; q < 4; ++q) {
#pragma unroll
        for (int r = 0; r < 4; ++r) {
          const int code = cg + 8 * q + r;
          const float vA = accA[4 * q + r];
          const bool cA = vA > bestA;
          bestA = cA ? vA : bestA;
          biA   = cA ? code : biA;
          const float vB = accB[4 * q + r];
          const bool cB = vB > bestB;
          bestB = cB ? vB : bestB;
          biB   = cB ? code : biB;
        }
      }
    }
    // ---- 6) end-of-compute barrier (raw: no vmcnt drain) before next overwrite ----
    __builtin_amdgcn_sched_barrier(0);
    __builtin_amdgcn_s_barrier();
    __builtin_amdgcn_sched_barrier(0);
  }

  // combine the two half-code-sets (lanes l and l^32 share x-row = lane&31)
  {
    const float ob = __shfl_xor(bestA, 32, 64);
    const int   oi = __shfl_xor(biA,   32, 64);
    if (ob > bestA || (ob == bestA && oi < biA)) { bestA = ob; biA = oi; }
  }
  {
    const float ob = __shfl_xor(bestB, 32, 64);
    const int   oi = __shfl_xor(biB,   32, 64);
    if (ob > bestB || (ob == bestB && oi < biB)) { bestB = ob; biB = oi; }
  }
  if (lane < 32) {
    // bijective monotone float->uint transform: unsigned order == float order
    const float distA = -2.0f * bestA;   // can be negative
    unsigned int dA = __float_as_uint(distA);
    dA ^= (unsigned int)((int)dA >> 31) | 0x80000000u;
    atomicMin(rowkey + myrow0,
              ((unsigned long long)dA << 32) | (unsigned int)biA);
    const float distB = -2.0f * bestB;
    unsigned int dB = __float_as_uint(distB);
    dB ^= (unsigned int)((int)dB >> 31) | 0x80000000u;
    atomicMin(rowkey + myrow1,
              ((unsigned long long)dB << 32) | (unsigned int)biB);
  }
}

// ---------------- per-row finalize: scatter, gather, loss + 32MB zero share ----------------
__global__ __launch_bounds__(256) void vq_finalize_rows_kernel(
    const float* __restrict__ x, const float* __restrict__ cb,
    const unsigned long long* __restrict__ rowkey,
    int* __restrict__ hist, float* __restrict__ lossSum,
    float* __restrict__ outp) {
  const int row = blockIdx.x * 256 + threadIdx.x;
  const int bi = (int)(rowkey[row] & 0xFFFFFFFFull);

  // 32 MB encodings zero share (NT), issued first (drains under the gather work below).
  // Ones for rows >= ROW_LATE (which may land in THIS region) are written by the
  // scalars kernel afterwards -> no intra-kernel race.
  {
    vfloat4* zp = (vfloat4*)(outp + ZBASE) + ZF4_FIN_BASE + row;
    const vfloat4 zz = (vfloat4)(0.0f);
#pragma unroll
    for (int j = 0; j < 128; ++j)
      __builtin_nontemporal_store(zz, zp + (size_t)j * 16384);
  }

  atomicAdd(hist + bi, 1);
  if (row < ROW_LATE)
    outp[(size_t)OFF_E + (size_t)row * K_CODES + bi] = 1.0f;

  const float4* ecb = reinterpret_cast<const float4*>(cb + ((size_t)bi << 6));
  const float4* xv  = reinterpret_cast<const float4*>(x + ((size_t)row << 6));
  float* q = outp + OFF_Q + (size_t)row * DIM;  // only 4B-aligned -> scalar stores
  float ls = 0.f;
#pragma unroll
  for (int i = 0; i < DIM / 4; ++i) {
    const float4 ev = ecb[i];
    const float4 xw = xv[i];
    q[i * 4 + 0] = ev.x;
    q[i * 4 + 1] = ev.y;
    q[i * 4 + 2] = ev.z;
    q[i * 4 + 3] = ev.w;
    const float d0 = ev.x - xw.x, d1 = ev.y - xw.y;
    const float d2 = ev.z - xw.z, d3 = ev.w - xw.w;
    ls = fmaf(d0, d0, ls);
    ls = fmaf(d1, d1, ls);
    ls = fmaf(d2, d2, ls);
    ls = fmaf(d3, d3, ls);
  }
  // per-wave reduction, one atomic per wave
#pragma unroll
  for (int off = 32; off > 0; off >>= 1) ls += __shfl_down(ls, off, 64);
  if ((threadIdx.x & 63) == 0) atomicAdd(lossSum, ls);
}

// ---------------- scalars: loss + perplexity; late one-hots parallel over 8 blocks ------
__global__ __launch_bounds__(256) void vq_scalars_kernel(
    const int* __restrict__ hist, const float* __restrict__ lossSum,
    const unsigned long long* __restrict__ rowkey,
    float* __restrict__ outp) {
  // late one-hots (rows whose encodings f4 may fall in finalize's zero region),
  // distributed across all 8 blocks
  {
    const int idx = blockIdx.x * 256 + threadIdx.x;   // 0..2047
    const int r = ROW_LATE + idx;
    if (r < N_ROWS) {
      const int bi = (int)(rowkey[r] & 0xFFFFFFFFull);
      outp[(size_t)OFF_E + (size_t)r * K_CODES + bi] = 1.0f;
    }
  }
  if (blockIdx.x != 0) return;

  __shared__ float red[256];
  float s = 0.f;
  for (int k = threadIdx.x; k < K_CODES; k += 256) {
    const float p = (float)hist[k] * (1.0f / (float)N_ROWS);
    s += p * logf(p + 1e-10f);
  }
  red[threadIdx.x] = s;
  __syncthreads();
  for (int off = 128; off > 0; off >>= 1) {
    if (threadIdx.x < off) red[threadIdx.x] += red[threadIdx.x + off];
    __syncthreads();
  }
  if (threadIdx.x == 0) {
    outp[OFF_P] = expf(-red[0]);
    outp[OFF_LOSS] = 0.25f * lossSum[0] * (1.0f / 1048576.0f);
  }
}

extern "C" void kernel_launch(void* const* d_in, const int* in_sizes, int n_in,
                              void* d_out, int out_size, void* d_ws, size_t ws_size,
                              hipStream_t stream) {
  const float* x  = (const float*)d_in[0];   // [16384, 64]
  const float* cb = (const float*)d_in[1];   // [8192, 64]
  float* outp = (float*)d_out;

  char* wsb = (char*)d_ws;
  unsigned short* cs          = (unsigned short*)(wsb + WS_CS);
  float* e2h                  = (float*)(wsb + WS_E2H);
  unsigned long long* rowkey  = (unsigned long long*)(wsb + WS_KEY);
  int*   hist                 = (int*)(wsb + WS_HIST);
  float* lossSum              = (float*)(wsb + WS_LOSS);

  vq_prologue_kernel<<<256, 256, 0, stream>>>(cb, cs, e2h, rowkey, hist, lossSum, outp);
  vq_argmin_kernel<<<dim3(RBLK, SPLITS), 256, 0, stream>>>(x, cs, e2h, rowkey, outp);
  vq_finalize_rows_kernel<<<N_ROWS / 256, 256, 0, stream>>>(x, cb, rowkey, hist, lossSum, outp);
  vq_scalars_kernel<<<8, 256, 0, stream>>>(hist, lossSum, rowkey, outp);
}